// Round 6
// baseline (740.071 us; speedup 1.0000x reference)
//
#include <hip/hip_runtime.h>
#include <math.h>

#define T      512
#define NBATCH 512
#define IN_DIM 64
#define H      100

// tanh(a) = 1 - 2/(exp(2a)+1)  -- overflow-safe at both ends.
__device__ __forceinline__ float fast_tanh(float a) {
    float e = __expf(2.0f * a);
    return 1.0f - 2.0f / (e + 1.0f);
}

// VALU cross-lane add via DPP quad-perm (replaces ds_bpermute shuffles)
#define DPP_XOR1 0xB1   /* quad_perm(1,0,3,2) */
#define DPP_XOR2 0x4E   /* quad_perm(2,3,0,1) */
#define XADD(v, CTRL) { int ti_ = __builtin_amdgcn_update_dpp(0, __builtin_bit_cast(int, (v)), (CTRL), 0xF, 0xF, true); \
                        (v) += __builtin_bit_cast(float, ti_); }
// cross-quad (lane^4) add for t=8 groups, lane-predicated so L1h lanes add 0
#define XOR4ADD(v) { int ti_ = __builtin_amdgcn_ds_swizzle(__builtin_bit_cast(int, (v)), 0x101F); \
                     float tf_ = __builtin_bit_cast(float, ti_); (v) += isL2 ? tf_ : 0.f; }

// ---------------------------------------------------------------------------
// Block = 384 threads, one batch element, grid 512 (2 blocks/CU).
//  [0..199]   L2  : t=8,n=4 — 224-dot cat[h1(112)|h2(112)] -> h2 (25 grp x 8)
//  [200..299] L1h : t=4,n=4 — 112-dot h1@W1h -> h1 (with XP's p) (25 grp x 4)
//  [300..319] idle (run L1h path, writes suppressed)
//  [320..383] XP  : t=4,n=7 — 64-dot x(t+1)@W1x + b1 -> pbuf (16 grp x 4)
// Weights: 28 NAMED float4 regs/thread (112 VGPRs). Recurrent roles read the
// parity-0/1 cat buffers via 7 precomputed pointers + immediate offsets.
// ---------------------------------------------------------------------------

#define W28(X) X(0) X(1) X(2) X(3) X(4) X(5) X(6) X(7) X(8) X(9) X(10) X(11) X(12) X(13) \
               X(14) X(15) X(16) X(17) X(18) X(19) X(20) X(21) X(22) X(23) X(24) X(25) X(26) X(27)

__device__ __forceinline__ float getw_rec(const float* __restrict__ WA,
                                          const float* __restrict__ WB,
                                          int r, int c) {
    // cat rows: [0..99]=WA, [100..111]=0, [112..211]=WB, [212..223]=0
    float va = WA[((r < H) ? r : (H - 1)) * H + c];
    int rb = r - 112;
    float vb = WB[((rb < 0) ? 0 : ((rb < H) ? rb : (H - 1))) * H + c];
    return (r < 112) ? ((r < H) ? va : 0.f) : ((r < 212) ? vb : 0.f);
}

#define RLOAD(i) { const int k_ = (i) >> 2, n_ = (i) & 3;                         \
    const int r_ = 4 * (s + tv * k_);                                             \
    w##i = make_float4(getw_rec(WA, WB, r_ + 0, colc + n_),                       \
                       getw_rec(WA, WB, r_ + 1, colc + n_),                       \
                       getw_rec(WA, WB, r_ + 2, colc + n_),                       \
                       getw_rec(WA, WB, r_ + 3, colc + n_)); }

#define XLOAD(i) { const int k_ = (i) / 7, n_ = (i) % 7;                          \
    const int r_ = 4 * (xs + 4 * k_);                                             \
    const int c_ = (7 * xg + n_ < H) ? (7 * xg + n_) : (H - 1);                   \
    w##i = make_float4(W1x[(r_ + 0) * H + c_], W1x[(r_ + 1) * H + c_],            \
                       W1x[(r_ + 2) * H + c_], W1x[(r_ + 3) * H + c_]); }

// recurrent dot step: one float4 chunk against 4 column-weight float4s
#define STEPR(V, WA_, WB_, WC_, WD_) { float4 v_ = (V);                            \
    a0 = fmaf(v_.x, (WA_).x, a0); a1 = fmaf(v_.x, (WB_).x, a1);                    \
    a2 = fmaf(v_.x, (WC_).x, a2); a3 = fmaf(v_.x, (WD_).x, a3);                    \
    a0 = fmaf(v_.y, (WA_).y, a0); a1 = fmaf(v_.y, (WB_).y, a1);                    \
    a2 = fmaf(v_.y, (WC_).y, a2); a3 = fmaf(v_.y, (WD_).y, a3);                    \
    a0 = fmaf(v_.z, (WA_).z, a0); a1 = fmaf(v_.z, (WB_).z, a1);                    \
    a2 = fmaf(v_.z, (WC_).z, a2); a3 = fmaf(v_.z, (WD_).z, a3);                    \
    a0 = fmaf(v_.w, (WA_).w, a0); a1 = fmaf(v_.w, (WB_).w, a1);                    \
    a2 = fmaf(v_.w, (WC_).w, a2); a3 = fmaf(v_.w, (WD_).w, a3); }

#define RDOT(OFS)                                                                  \
    float a0 = 0.f, a1 = 0.f, a2 = 0.f, a3 = 0.f;                                  \
    STEPR(pk0[OFS], w0,  w1,  w2,  w3)                                             \
    STEPR(pk1[OFS], w4,  w5,  w6,  w7)                                             \
    STEPR(pk2[OFS], w8,  w9,  w10, w11)                                            \
    STEPR(pk3[OFS], w12, w13, w14, w15)                                            \
    STEPR(pk4[OFS], w16, w17, w18, w19)                                            \
    STEPR(pk5[OFS], w20, w21, w22, w23)                                            \
    STEPR(pk6[OFS], w24, w25, w26, w27)

// XP dot step: one x-chunk (register) against 7 column-weight float4s
#define STEPX(V, W0_, W1_, W2_, W3_, W4_, W5_, W6_) { float4 v_ = (V);             \
    e0 = fmaf(v_.x, (W0_).x, e0); e1 = fmaf(v_.x, (W1_).x, e1);                    \
    e2 = fmaf(v_.x, (W2_).x, e2); e3 = fmaf(v_.x, (W3_).x, e3);                    \
    e4 = fmaf(v_.x, (W4_).x, e4); e5 = fmaf(v_.x, (W5_).x, e5);                    \
    e6 = fmaf(v_.x, (W6_).x, e6);                                                  \
    e0 = fmaf(v_.y, (W0_).y, e0); e1 = fmaf(v_.y, (W1_).y, e1);                    \
    e2 = fmaf(v_.y, (W2_).y, e2); e3 = fmaf(v_.y, (W3_).y, e3);                    \
    e4 = fmaf(v_.y, (W4_).y, e4); e5 = fmaf(v_.y, (W5_).y, e5);                    \
    e6 = fmaf(v_.y, (W6_).y, e6);                                                  \
    e0 = fmaf(v_.z, (W0_).z, e0); e1 = fmaf(v_.z, (W1_).z, e1);                    \
    e2 = fmaf(v_.z, (W2_).z, e2); e3 = fmaf(v_.z, (W3_).z, e3);                    \
    e4 = fmaf(v_.z, (W4_).z, e4); e5 = fmaf(v_.z, (W5_).z, e5);                    \
    e6 = fmaf(v_.z, (W6_).z, e6);                                                  \
    e0 = fmaf(v_.w, (W0_).w, e0); e1 = fmaf(v_.w, (W1_).w, e1);                    \
    e2 = fmaf(v_.w, (W2_).w, e2); e3 = fmaf(v_.w, (W3_).w, e3);                    \
    e4 = fmaf(v_.w, (W4_).w, e4); e5 = fmaf(v_.w, (W5_).w, e5);                    \
    e6 = fmaf(v_.w, (W6_).w, e6); }

// full XP body: dot + butterfly + biased write into DST (pbuf slot)
#define XPBODY(DST) {                                                              \
    float e0 = 0.f, e1 = 0.f, e2 = 0.f, e3 = 0.f, e4 = 0.f, e5 = 0.f, e6 = 0.f;    \
    STEPX(xr0, w0,  w1,  w2,  w3,  w4,  w5,  w6)                                   \
    STEPX(xr1, w7,  w8,  w9,  w10, w11, w12, w13)                                  \
    STEPX(xr2, w14, w15, w16, w17, w18, w19, w20)                                  \
    STEPX(xr3, w21, w22, w23, w24, w25, w26, w27)                                  \
    XADD(e0, DPP_XOR1) XADD(e1, DPP_XOR1) XADD(e2, DPP_XOR1) XADD(e3, DPP_XOR1)    \
    XADD(e4, DPP_XOR1) XADD(e5, DPP_XOR1) XADD(e6, DPP_XOR1)                       \
    XADD(e0, DPP_XOR2) XADD(e1, DPP_XOR2) XADD(e2, DPP_XOR2) XADD(e3, DPP_XOR2)    \
    XADD(e4, DPP_XOR2) XADD(e5, DPP_XOR2) XADD(e6, DPP_XOR2)                       \
    float v1_ = (xs & 1) ? ((xs & 2) ? e3 : e1) : ((xs & 2) ? e2 : e0);            \
    float v2_ = (xs & 1) ? e5 : ((xs & 2) ? e6 : e4);                              \
    (DST)[7 * xg + xs] = v1_ + bx1;                                                \
    if (xs < 3) (DST)[7 * xg + 4 + xs] = v2_ + bx2; }

// recurrent body: dot + butterfly(+xor4 for L2) + finalize + store
#define RBODY(OFS, PV, ST, L2GUARD) {                                              \
    RDOT(OFS)                                                                      \
    XADD(a0, DPP_XOR1) XADD(a1, DPP_XOR1) XADD(a2, DPP_XOR1) XADD(a3, DPP_XOR1)    \
    XADD(a0, DPP_XOR2) XADD(a1, DPP_XOR2) XADD(a2, DPP_XOR2) XADD(a3, DPP_XOR2)    \
    if (tid < 256) { XOR4ADD(a0) XOR4ADD(a1) XOR4ADD(a2) XOR4ADD(a3) }             \
    float val = (s & 1) ? ((s & 2) ? a3 : a1) : ((s & 2) ? a2 : a0);               \
    float pv_ = (PV)[0];                                                           \
    val = fast_tanh(val + (isL2 ? b2v : pv_));                                     \
    if (wr && (L2GUARD)) *(ST) = val; }

__global__ __launch_bounds__(384, 3)
void drnn_kernel(const float* __restrict__ x,
                 const float* __restrict__ W1x, const float* __restrict__ W1h,
                 const float* __restrict__ b1,
                 const float* __restrict__ W2x, const float* __restrict__ W2h,
                 const float* __restrict__ b2,
                 const float* __restrict__ Wo,  const float* __restrict__ bo,
                 float* __restrict__ out)
{
    // parity-indexed cat state: [h1(100) pad112 | h2(100) pad112] = 56 float4
    __shared__ __align__(16) float4 lds4[2][56];
    __shared__ float pbuf[2][112];    // x@W1x + b1, one step ahead

    const int tid = threadIdx.x;
    const int b   = blockIdx.x;
    const float* __restrict__ xrow = x + (size_t)b * T * IN_DIM;
    float* lds0 = (float*)&lds4[0][0];
    float* lds1 = (float*)&lds4[1][0];

    // ---- zero-init both cat buffers (pads must stay 0; h(-1)=0) ----
    for (int k = tid; k < 448; k += 384) ((float*)lds4)[k] = 0.f;

    // ---- roles ----
    const bool isRec = (tid < 320);
    const bool isL2  = (tid < 200);
    const int  idx   = isL2 ? tid : (tid - 200);
    const int  tv    = isL2 ? 8 : 4;                    // K-split width
    const int  g     = isL2 ? (tid >> 3) : (idx >> 2);  // neuron group
    const int  s     = isL2 ? (tid & 7)  : (idx & 3);   // K-split lane
    const int  colb  = 4 * g;
    const int  colc  = (colb < 96) ? colb : 96;          // clamped for loads
    const bool wr    = isRec && (isL2 ? (s < 4) : (idx < 100));
    const int  colw  = colb + (s & 3);
    const int  colp  = (colw < H) ? colw : (H - 1);

    const int  xidx = tid - 320;                         // XP role (wave 5)
    const int  xg   = (xidx >= 0) ? (xidx >> 2) : 0;
    const int  xs   = (xidx >= 0) ? (xidx & 3) : 0;

    const float* __restrict__ WA = isL2 ? W2x : W1h;
    const float* __restrict__ WB = W2h;
    const float b2v = b2[colp];
    float bx1 = 0.f, bx2 = 0.f;

    // ---- 28 named float4 weight registers ----
    float4 w0,  w1,  w2,  w3,  w4,  w5,  w6,  w7,  w8,  w9,  w10, w11, w12, w13;
    float4 w14, w15, w16, w17, w18, w19, w20, w21, w22, w23, w24, w25, w26, w27;
    float4 xr0, xr1, xr2, xr3;   // XP x prefetch (x(t+1))
    xr0 = xr1 = xr2 = xr3 = make_float4(0.f, 0.f, 0.f, 0.f);

    if (isRec) {
        W28(RLOAD)
    } else {
        W28(XLOAD)
        bx1 = b1[(7 * xg + xs < H) ? (7 * xg + xs) : (H - 1)];
        bx2 = b1[(7 * xg + 4 + xs < H) ? (7 * xg + 4 + xs) : (H - 1)];
    }

    // ---- 7 chunk pointers into parity-0 cat; parity-1 = +56 float4 imm ----
    const float4* pk0 = &lds4[0][s + tv * 0];
    const float4* pk1 = &lds4[0][s + tv * 1];
    const float4* pk2 = &lds4[0][s + tv * 2];
    const float4* pk3 = &lds4[0][s + tv * 3];
    const float4* pk4 = &lds4[0][s + tv * 4];
    const float4* pk5 = &lds4[0][s + tv * 5];
    const float4* pk6 = &lds4[0][s + tv * 6];
    const float* pv_e = &pbuf[0][colp];
    const float* pv_o = &pbuf[1][colp];
    float* st_e = isL2 ? (lds1 + 112 + colw) : (lds1 + colw);
    float* st_o = isL2 ? (lds0 + 112 + colw) : (lds0 + colw);

    // ---- XP prologue: p(0) -> pbuf[0]; then prefetch x(1) ----
    if (!isRec) {
        const float* xp_ = xrow;                         // x(0)
        xr0 = *(const float4*)(xp_ + 4 * xs);
        xr1 = *(const float4*)(xp_ + 4 * xs + 16);
        xr2 = *(const float4*)(xp_ + 4 * xs + 32);
        xr3 = *(const float4*)(xp_ + 4 * xs + 48);
        XPBODY(pbuf[0])
        const float* xq_ = xrow + IN_DIM;                // x(1)
        xr0 = *(const float4*)(xq_ + 4 * xs);
        xr1 = *(const float4*)(xq_ + 4 * xs + 16);
        xr2 = *(const float4*)(xq_ + 4 * xs + 32);
        xr3 = *(const float4*)(xq_ + 4 * xs + 48);
    }
    __syncthreads();

    // Iter i: L1h -> h1(i), L2 -> h2(i-1), XP -> p(i+1).
    #pragma unroll 1
    for (int i = 0; i < T; i += 2) {
        // ---- even body: read parity 0, write parity 1 ----
        if (isRec) {
            RBODY(0, pv_e, st_e, (!isL2 || i > 0))
        } else {
            XPBODY(pbuf[1])
            if (i + 2 < T) {
                const float* xq_ = xrow + (size_t)(i + 2) * IN_DIM;
                xr0 = *(const float4*)(xq_ + 4 * xs);
                xr1 = *(const float4*)(xq_ + 4 * xs + 16);
                xr2 = *(const float4*)(xq_ + 4 * xs + 32);
                xr3 = *(const float4*)(xq_ + 4 * xs + 48);
            }
        }
        __syncthreads();
        // ---- odd body: read parity 1, write parity 0 ----
        if (isRec) {
            RBODY(56, pv_o, st_o, true)
        } else {
            XPBODY(pbuf[0])
            if (i + 3 < T) {
                const float* xq_ = xrow + (size_t)(i + 3) * IN_DIM;
                xr0 = *(const float4*)(xq_ + 4 * xs);
                xr1 = *(const float4*)(xq_ + 4 * xs + 16);
                xr2 = *(const float4*)(xq_ + 4 * xs + 32);
                xr3 = *(const float4*)(xq_ + 4 * xs + 48);
            }
        }
        __syncthreads();
    }

    // ---- tail: L2 computes h2(T-1) from lds[0] = {h1(T-1), h2(T-2)} ----
    if (isL2) {
        RDOT(0)
        XADD(a0, DPP_XOR1) XADD(a1, DPP_XOR1) XADD(a2, DPP_XOR1) XADD(a3, DPP_XOR1)
        XADD(a0, DPP_XOR2) XADD(a1, DPP_XOR2) XADD(a2, DPP_XOR2) XADD(a3, DPP_XOR2)
        XOR4ADD(a0) XOR4ADD(a1) XOR4ADD(a2) XOR4ADD(a3)
        float val = (s & 1) ? ((s & 2) ? a3 : a1) : ((s & 2) ? a2 : a0);
        val = fast_tanh(val + b2v);
        if (s < 4) lds1[112 + colw] = val;               // h2(T-1)
    }
    __syncthreads();

    // ---- epilogue: h1(T-1) = lds0[0..100), h2(T-1) = lds1[112..212) ----
    if (tid < H)
        out[NBATCH + (size_t)b * H + tid] = lds0[tid];
    if (tid < H)
        out[NBATCH + (size_t)NBATCH * H + (size_t)b * H + tid] = lds1[112 + tid];

    // out[b] = h2_T . Wo + bo  (wave-0 shuffle reduction)
    if (tid < 64) {
        float v = lds1[112 + tid] * Wo[tid];
        if (tid < H - 64) v += lds1[112 + 64 + tid] * Wo[tid + 64];
        #pragma unroll
        for (int off = 32; off >= 1; off >>= 1) v += __shfl_down(v, off);
        if (tid == 0) out[b] = v + bo[0];
    }
}

extern "C" void kernel_launch(void* const* d_in, const int* in_sizes, int n_in,
                              void* d_out, int out_size, void* d_ws, size_t ws_size,
                              hipStream_t stream) {
    const float* x   = (const float*)d_in[0];
    const float* W1x = (const float*)d_in[1];
    const float* W1h = (const float*)d_in[2];
    const float* b1  = (const float*)d_in[3];
    const float* W2x = (const float*)d_in[4];
    const float* W2h = (const float*)d_in[5];
    const float* b2  = (const float*)d_in[6];
    const float* Wo  = (const float*)d_in[7];
    const float* bo  = (const float*)d_in[8];
    float* out = (float*)d_out;

    drnn_kernel<<<NBATCH, 384, 0, stream>>>(x, W1x, W1h, b1, W2x, W2h, b2,
                                            Wo, bo, out);
}

// Round 7
// 656.074 us; speedup vs baseline: 1.1280x; 1.1280x over previous
//
#include <hip/hip_runtime.h>
#include <math.h>

#define T      512
#define NBATCH 512
#define IN_DIM 64
#define H      100
#define MB     16          // batch rows per block (MFMA M)
#define NW     7           // waves per block = N-tiles of 16 (100 -> 112 pad)
#define NTHR   (NW * 64)   // 448

typedef __attribute__((ext_vector_type(8))) _Float16 v8h;
typedef __attribute__((ext_vector_type(4))) float    v4f;

#define MF(A, B, C) (C) = __builtin_amdgcn_mfma_f32_16x16x32_f16((A), (B), (C), 0, 0, 0)
#define SLO (1.0f / 4096.0f)

// tanh(a) = 1 - 2/(exp(2a)+1) -- overflow-safe at both ends.
__device__ __forceinline__ float fast_tanh(float a) {
    float e = __expf(2.0f * a);
    return 1.0f - 2.0f / (e + 1.0f);
}
__device__ __forceinline__ unsigned short f16b(float v) {
    _Float16 h = (_Float16)v;                 // RNE
    return __builtin_bit_cast(unsigned short, h);
}
__device__ __forceinline__ float f16f(unsigned short u) {
    _Float16 h = __builtin_bit_cast(_Float16, u);
    return (float)h;
}
__device__ __forceinline__ float wget(const float* __restrict__ W, int k, int kv,
                                      int colc, bool colok) {
    float v = W[((k < kv) ? k : 0) * H + colc];
    return (k < kv && colok) ? v : 0.f;
}

// Build B-frag pair for one 32-K chunk: HI = f16(W), LO = f16((W - HI)*4096).
// B layout (16x16x32): n = lane&15 (col), k = KB + 8*quad + j.
#define WCHUNK(HI, LO, WP, KB, KV) {                                          \
    float g0 = wget(WP, (KB) + kq + 0, KV, colc, colok);                       \
    float g1 = wget(WP, (KB) + kq + 1, KV, colc, colok);                       \
    float g2 = wget(WP, (KB) + kq + 2, KV, colc, colok);                       \
    float g3 = wget(WP, (KB) + kq + 3, KV, colc, colok);                       \
    float g4 = wget(WP, (KB) + kq + 4, KV, colc, colok);                       \
    float g5 = wget(WP, (KB) + kq + 5, KV, colc, colok);                       \
    float g6 = wget(WP, (KB) + kq + 6, KV, colc, colok);                       \
    float g7 = wget(WP, (KB) + kq + 7, KV, colc, colok);                       \
    HI = (v8h){(_Float16)g0, (_Float16)g1, (_Float16)g2, (_Float16)g3,         \
               (_Float16)g4, (_Float16)g5, (_Float16)g6, (_Float16)g7};        \
    LO = (v8h){(_Float16)((g0 - (float)(_Float16)g0) * 4096.f),                \
               (_Float16)((g1 - (float)(_Float16)g1) * 4096.f),                \
               (_Float16)((g2 - (float)(_Float16)g2) * 4096.f),                \
               (_Float16)((g3 - (float)(_Float16)g3) * 4096.f),                \
               (_Float16)((g4 - (float)(_Float16)g4) * 4096.f),                \
               (_Float16)((g5 - (float)(_Float16)g5) * 4096.f),                \
               (_Float16)((g6 - (float)(_Float16)g6) * 4096.f),                \
               (_Float16)((g7 - (float)(_Float16)g7) * 4096.f)};               \
}

#define XFRAG(DST, A, B) DST = (v8h){(_Float16)(A).x, (_Float16)(A).y,         \
    (_Float16)(A).z, (_Float16)(A).w, (_Float16)(B).x, (_Float16)(B).y,        \
    (_Float16)(B).z, (_Float16)(B).w};

// ---------------------------------------------------------------------------
// 32 blocks x 448 threads. Block owns 16 batch rows; wave w owns neuron
// cols 16w..16w+15 of BOTH layers (pipelined: body i does L1->h1(i) and
// L2->h2(i-1); 1 barrier/body). h-state lives in LDS pre-swizzled in MFMA
// A-frag order ([parity][chunk][lane] 16B frags, f16). Weights: 28 named
// v8h B-frags/thread, split W = Whi + 2^-12*Wlo (Wlo scaled past f16
// denormals), fp32 MFMA accumulate -> per-step quant error ~3e-4.
// ---------------------------------------------------------------------------
__global__ __launch_bounds__(NTHR, 2)
void drnn_kernel(const float* __restrict__ x,
                 const float* __restrict__ W1x, const float* __restrict__ W1h,
                 const float* __restrict__ b1,
                 const float* __restrict__ W2x, const float* __restrict__ W2h,
                 const float* __restrict__ b2,
                 const float* __restrict__ Wo,  const float* __restrict__ bo,
                 float* __restrict__ out)
{
    __shared__ __align__(16) v8h A1[2 * 4 * 64];   // h1 frags [parity][chunk][lane]
    __shared__ __align__(16) v8h A2[2 * 4 * 64];   // h2 frags
    unsigned short* usA1 = (unsigned short*)A1;
    unsigned short* usA2 = (unsigned short*)A2;

    const int tid  = threadIdx.x;
    const int lane = tid & 63;
    const int quad = lane >> 4;
    const int kq   = 8 * quad;
    const int wv   = tid >> 6;            // N-tile
    const int m    = lane & 15;           // batch row (A/C row)
    const int b0   = blockIdx.x * MB;

    // zero LDS (h(-1)=h(-2)=0; K-pad rows 100..127 stay 0 forever)
    for (int k = tid; k < 2 * 4 * 64 * 4; k += NTHR) {
        ((int*)A1)[k] = 0; ((int*)A2)[k] = 0;
    }

    const int  col   = 16 * wv + (lane & 15);
    const bool colok = (col < H);
    const int  colc  = colok ? col : (H - 1);
    const float b1v  = b1[colc];
    const float b2v  = b2[colc];
    // producer ushort base: element [m=4q+r][k=col] -> +8 per r
    const int cb = (col >> 5) * 512 + ((col >> 3) & 3) * 128 + 32 * quad + (col & 7);

    // ---- 28 named v8h weight B-frags ----
    v8h wx0h, wx0l, wx1h, wx1l;                    // W1x (K=64, 2 chunks)
    v8h wh0h, wh0l, wh1h, wh1l, wh2h, wh2l, wh3h, wh3l;   // W1h
    v8h wa0h, wa0l, wa1h, wa1l, wa2h, wa2l, wa3h, wa3l;   // W2x
    v8h wb0h, wb0l, wb1h, wb1l, wb2h, wb2l, wb3h, wb3l;   // W2h
    WCHUNK(wx0h, wx0l, W1x,  0, IN_DIM)
    WCHUNK(wx1h, wx1l, W1x, 32, IN_DIM)
    WCHUNK(wh0h, wh0l, W1h,  0, H)
    WCHUNK(wh1h, wh1l, W1h, 32, H)
    WCHUNK(wh2h, wh2l, W1h, 64, H)
    WCHUNK(wh3h, wh3l, W1h, 96, H)
    WCHUNK(wa0h, wa0l, W2x,  0, H)
    WCHUNK(wa1h, wa1l, W2x, 32, H)
    WCHUNK(wa2h, wa2l, W2x, 64, H)
    WCHUNK(wa3h, wa3l, W2x, 96, H)
    WCHUNK(wb0h, wb0l, W2h,  0, H)
    WCHUNK(wb1h, wb1l, W2h, 32, H)
    WCHUNK(wb2h, wb2l, W2h, 64, H)
    WCHUNK(wb3h, wb3l, W2h, 96, H)

    // ---- x prefetch (A-frag source): lane covers x[b0+m][8q.. / 32+8q..] ----
    const float* __restrict__ xbase =
        x + ((size_t)(b0 + m) * T) * IN_DIM + kq;
    float4 cxa = *(const float4*)(xbase);          // x(0) chunk0 lo
    float4 cxb = *(const float4*)(xbase + 4);      //       chunk0 hi
    float4 cxc = *(const float4*)(xbase + 32);     //       chunk1 lo
    float4 cxd = *(const float4*)(xbase + 36);

    __syncthreads();

    #pragma unroll 1
    for (int i = 0; i < T; ++i) {
        const int p  = i & 1;
        const int rb = p ? 256 : 0;       // frag read base (v8h units)
        const int wb = p ? 0 : 2048;      // ushort write base (parity p^1)

        // A-frags: h1(i-1), h2(i-2)
        v8h h10 = A1[rb + lane],       h11 = A1[rb + 64 + lane];
        v8h h12 = A1[rb + 128 + lane], h13 = A1[rb + 192 + lane];
        v8h h20 = A2[rb + lane],       h21 = A2[rb + 64 + lane];
        v8h h22 = A2[rb + 128 + lane], h23 = A2[rb + 192 + lane];

        v8h ax0, ax1;
        XFRAG(ax0, cxa, cxb)
        XFRAG(ax1, cxc, cxd)

        // ---- L1: h1(i) = tanh(x(i)@W1x + h1(i-1)@W1h + b1) ----
        v4f t1 = {0.f, 0.f, 0.f, 0.f}, t2 = {0.f, 0.f, 0.f, 0.f};
        MF(ax0, wx0h, t1); MF(ax1, wx1h, t1);
        MF(h10, wh0h, t1); MF(h11, wh1h, t1); MF(h12, wh2h, t1); MF(h13, wh3h, t1);
        MF(ax0, wx0l, t2); MF(ax1, wx1l, t2);
        MF(h10, wh0l, t2); MF(h11, wh1l, t2); MF(h12, wh2l, t2); MF(h13, wh3l, t2);

        // ---- L2: h2(i-1) = tanh(h1(i-1)@W2x + h2(i-2)@W2h + b2) ----
        v4f u1 = {0.f, 0.f, 0.f, 0.f}, u2 = {0.f, 0.f, 0.f, 0.f};
        MF(h10, wa0h, u1); MF(h11, wa1h, u1); MF(h12, wa2h, u1); MF(h13, wa3h, u1);
        MF(h20, wb0h, u1); MF(h21, wb1h, u1); MF(h22, wb2h, u1); MF(h23, wb3h, u1);
        MF(h10, wa0l, u2); MF(h11, wa1l, u2); MF(h12, wa2l, u2); MF(h13, wa3l, u2);
        MF(h20, wb0l, u2); MF(h21, wb1l, u2); MF(h22, wb2l, u2); MF(h23, wb3l, u2);

        // prefetch x(i+1) (consumed next body; clamp keeps addr in-bounds)
        {
            const float* xp = xbase + (size_t)((i + 1 < T) ? (i + 1) : (T - 1)) * IN_DIM;
            cxa = *(const float4*)(xp);
            cxb = *(const float4*)(xp + 4);
            cxc = *(const float4*)(xp + 32);
            cxd = *(const float4*)(xp + 36);
        }

        // finalize + store (C/D: col=lane&15, row=quad*4+r)
        if (colok) {
            float d0 = fast_tanh(t1[0] + t2[0] * SLO + b1v);
            float d1 = fast_tanh(t1[1] + t2[1] * SLO + b1v);
            float d2 = fast_tanh(t1[2] + t2[2] * SLO + b1v);
            float d3 = fast_tanh(t1[3] + t2[3] * SLO + b1v);
            usA1[wb + cb]      = f16b(d0);
            usA1[wb + cb + 8]  = f16b(d1);
            usA1[wb + cb + 16] = f16b(d2);
            usA1[wb + cb + 24] = f16b(d3);
            if (i > 0) {   // skip bogus h2(-1): A2 parity-1 must stay 0
                float e0 = fast_tanh(u1[0] + u2[0] * SLO + b2v);
                float e1 = fast_tanh(u1[1] + u2[1] * SLO + b2v);
                float e2 = fast_tanh(u1[2] + u2[2] * SLO + b2v);
                float e3 = fast_tanh(u1[3] + u2[3] * SLO + b2v);
                usA2[wb + cb]      = f16b(e0);
                usA2[wb + cb + 8]  = f16b(e1);
                usA2[wb + cb + 16] = f16b(e2);
                usA2[wb + cb + 24] = f16b(e3);
            }
        }
        __syncthreads();
    }

    // ---- tail (i=T, p=0): L2 only -> h2(T-1) into A2 parity 1 ----
    {
        v8h h10 = A1[lane],       h11 = A1[64 + lane];
        v8h h12 = A1[128 + lane], h13 = A1[192 + lane];
        v8h h20 = A2[lane],       h21 = A2[64 + lane];
        v8h h22 = A2[128 + lane], h23 = A2[192 + lane];
        v4f u1 = {0.f, 0.f, 0.f, 0.f}, u2 = {0.f, 0.f, 0.f, 0.f};
        MF(h10, wa0h, u1); MF(h11, wa1h, u1); MF(h12, wa2h, u1); MF(h13, wa3h, u1);
        MF(h20, wb0h, u1); MF(h21, wb1h, u1); MF(h22, wb2h, u1); MF(h23, wb3h, u1);
        MF(h10, wa0l, u2); MF(h11, wa1l, u2); MF(h12, wa2l, u2); MF(h13, wa3l, u2);
        MF(h20, wb0l, u2); MF(h21, wb1l, u2); MF(h22, wb2l, u2); MF(h23, wb3l, u2);
        if (colok) {
            float e0 = fast_tanh(u1[0] + u2[0] * SLO + b2v);
            float e1 = fast_tanh(u1[1] + u2[1] * SLO + b2v);
            float e2 = fast_tanh(u1[2] + u2[2] * SLO + b2v);
            float e3 = fast_tanh(u1[3] + u2[3] * SLO + b2v);
            usA2[2048 + cb]      = f16b(e0);
            usA2[2048 + cb + 8]  = f16b(e1);
            usA2[2048 + cb + 16] = f16b(e2);
            usA2[2048 + cb + 24] = f16b(e3);
        }
    }
    __syncthreads();

    // ---- epilogue: h1(T-1) in A1 parity 0, h2(T-1) in A2 parity 1 ----
    for (int t = tid; t < MB * H; t += NTHR) {
        int mm = t / H, n = t % H;
        int ix = (n >> 5) * 512 + ((n >> 3) & 3) * 128 + 8 * mm + (n & 7);
        out[NBATCH + (size_t)(b0 + mm) * H + n] = f16f(usA1[ix]);
        out[NBATCH + (size_t)NBATCH * H + (size_t)(b0 + mm) * H + n] =
            f16f(usA2[2048 + ix]);
    }
    if (tid < MB) {
        float acc = bo[0];
        for (int n = 0; n < H; ++n) {
            int ix = 2048 + (n >> 5) * 512 + ((n >> 3) & 3) * 128 + 8 * tid + (n & 7);
            acc += f16f(usA2[ix]) * Wo[n];
        }
        out[b0 + tid] = acc;
    }
}

extern "C" void kernel_launch(void* const* d_in, const int* in_sizes, int n_in,
                              void* d_out, int out_size, void* d_ws, size_t ws_size,
                              hipStream_t stream) {
    const float* x   = (const float*)d_in[0];
    const float* W1x = (const float*)d_in[1];
    const float* W1h = (const float*)d_in[2];
    const float* b1  = (const float*)d_in[3];
    const float* W2x = (const float*)d_in[4];
    const float* W2h = (const float*)d_in[5];
    const float* b2  = (const float*)d_in[6];
    const float* Wo  = (const float*)d_in[7];
    const float* bo  = (const float*)d_in[8];
    float* out = (float*)d_out;

    drnn_kernel<<<NBATCH / MB, NTHR, 0, stream>>>(x, W1x, W1h, b1, W2x, W2h, b2,
                                                  Wo, bo, out);
}